// Round 3
// baseline (8465.040 us; speedup 1.0000x reference)
//
#include <hip/hip_runtime.h>

#define NN 50000

// ---------------- degree / dinv ----------------
__global__ __launch_bounds__(256) void k_deg(const int* __restrict__ dst, int E,
                                             float* __restrict__ deg) {
    int e = blockIdx.x * 256 + threadIdx.x;
    if (e < E) atomicAdd(&deg[dst[e]], 1.0f);
}

__global__ __launch_bounds__(256) void k_dinv(const float* __restrict__ deg,
                                              float* __restrict__ dinv, int n) {
    int i = blockIdx.x * 256 + threadIdx.x;
    if (i < n) dinv[i] = rsqrtf(deg[i] + 1.0f);  // +1 self-loop
}

// ---------------- f32 tiled GEMM: C[M,N] = A[M,K] * B[K,N] ----------------
// BM=BN=64, BK=16, 256 threads, 4x4 microtile. K must be multiple of 16.
__global__ __launch_bounds__(256) void sgemm64(const float* __restrict__ A,
                                               const float* __restrict__ B,
                                               float* __restrict__ C,
                                               int M, int N, int K) {
    __shared__ float As[16][64];  // transposed: As[k][m]
    __shared__ float Bs[16][64];
    const int tid = threadIdx.x;
    const int bm = blockIdx.y * 64;
    const int bn = blockIdx.x * 64;
    const int ty = tid >> 4, tx = tid & 15;

    // A-load mapping: row = tid>>2 (0..63), k-seg = (tid&3)*4
    const int arow = tid >> 2, akk = (tid & 3) * 4;
    // B-load mapping: k-row = tid>>4 (0..15), col = (tid&15)*4
    const int brow = tid >> 4, bcol = (tid & 15) * 4;

    float acc[4][4] = {};

    for (int k0 = 0; k0 < K; k0 += 16) {
        float4 av = make_float4(0.f, 0.f, 0.f, 0.f);
        int gr = bm + arow;
        if (gr < M) av = *(const float4*)&A[(size_t)gr * K + k0 + akk];
        As[akk + 0][arow] = av.x;
        As[akk + 1][arow] = av.y;
        As[akk + 2][arow] = av.z;
        As[akk + 3][arow] = av.w;
        *(float4*)&Bs[brow][bcol] = *(const float4*)&B[(size_t)(k0 + brow) * N + bn + bcol];
        __syncthreads();
#pragma unroll
        for (int kk = 0; kk < 16; ++kk) {
            float4 a = *(const float4*)&As[kk][ty * 4];
            float4 b = *(const float4*)&Bs[kk][tx * 4];
            float ar[4] = {a.x, a.y, a.z, a.w};
            float br[4] = {b.x, b.y, b.z, b.w};
#pragma unroll
            for (int i = 0; i < 4; ++i)
#pragma unroll
                for (int j = 0; j < 4; ++j) acc[i][j] += ar[i] * br[j];
        }
        __syncthreads();
    }
#pragma unroll
    for (int i = 0; i < 4; ++i) {
        int gr = bm + ty * 4 + i;
        if (gr < M)
            *(float4*)&C[(size_t)gr * N + bn + tx * 4] =
                make_float4(acc[i][0], acc[i][1], acc[i][2], acc[i][3]);
    }
}

// ---------------- edge scatter: agg[dst] += h[src] * dinv[src]*dinv[dst] ----------------
template <int C>
__global__ __launch_bounds__(256) void k_scatter(const int* __restrict__ src,
                                                 const int* __restrict__ dst,
                                                 const float* __restrict__ h,
                                                 const float* __restrict__ dinv,
                                                 float* __restrict__ agg, int E) {
    constexpr int TPE = C / 4;        // threads per edge
    constexpr int EPB = 256 / TPE;    // edges per block
    const int local = threadIdx.x / TPE;
    const int lane = threadIdx.x % TPE;
    const int e = blockIdx.x * EPB + local;
    if (e >= E) return;
    const int s = src[e], d = dst[e];
    const float norm = dinv[s] * dinv[d];
    const float4 v = *(const float4*)&h[(size_t)s * C + lane * 4];
    float* o = &agg[(size_t)d * C + lane * 4];
    atomicAdd(o + 0, v.x * norm);
    atomicAdd(o + 1, v.y * norm);
    atomicAdd(o + 2, v.z * norm);
    atomicAdd(o + 3, v.w * norm);
}

// ---------------- finalize: out = relu(agg + h*dinv^2 + bias) ----------------
template <int C>
__global__ __launch_bounds__(256) void k_final(const float* __restrict__ agg,
                                               const float* __restrict__ h,
                                               const float* __restrict__ dinv,
                                               const float* __restrict__ bias,
                                               float* __restrict__ out, int n) {
    const int idx = blockIdx.x * 256 + threadIdx.x;
    const int total = n * (C / 4);
    if (idx >= total) return;
    const int i = idx / (C / 4);
    const int c4 = idx % (C / 4);
    const float di = dinv[i];
    const float d2 = di * di;
    float4 a = *(const float4*)&agg[(size_t)i * C + c4 * 4];
    float4 hv = *(const float4*)&h[(size_t)i * C + c4 * 4];
    float4 bv = *(const float4*)&bias[c4 * 4];
    float4 r;
    r.x = fmaxf(a.x + hv.x * d2 + bv.x, 0.f);
    r.y = fmaxf(a.y + hv.y * d2 + bv.y, 0.f);
    r.z = fmaxf(a.z + hv.z * d2 + bv.z, 0.f);
    r.w = fmaxf(a.w + hv.w * d2 + bv.w, 0.f);
    *(float4*)&out[(size_t)i * C + c4 * 4] = r;
}

extern "C" void kernel_launch(void* const* d_in, const int* in_sizes, int n_in,
                              void* d_out, int out_size, void* d_ws, size_t ws_size,
                              hipStream_t stream) {
    const float* x[2] = {(const float*)d_in[0], (const float*)d_in[2]};
    const int* eidx[2] = {(const int*)d_in[1], (const int*)d_in[3]};
    const int E[2] = {in_sizes[1] / 2, in_sizes[3] / 2};
    const float* W1 = (const float*)d_in[4];
    const float* b1 = (const float*)d_in[5];
    const float* W2 = (const float*)d_in[6];
    const float* b2 = (const float*)d_in[7];
    float* out = (float*)d_out;

    char* ws = (char*)d_ws;
    float* bufH = (float*)ws;                              // 50000*256 f32 (h1 then h2)
    float* bufA = (float*)(ws + (size_t)NN * 256 * 4);     // 50000*256 f32 (agg1/x1 then agg2)
    float* deg = (float*)(ws + (size_t)NN * 256 * 4 * 2);  // 50000 f32
    float* dinv = deg + NN;                                // 50000 f32

    for (int g = 0; g < 2; ++g) {
        const int Eg = E[g];
        const int* srcp = eidx[g];
        const int* dstp = eidx[g] + Eg;

        hipMemsetAsync(deg, 0, NN * sizeof(float), stream);
        k_deg<<<(Eg + 255) / 256, 256, 0, stream>>>(dstp, Eg, deg);
        k_dinv<<<(NN + 255) / 256, 256, 0, stream>>>(deg, dinv, NN);

        // ---- layer 1: h1 = x @ W1 ; agg over edges ; x1 = relu(agg + self + b1)
        sgemm64<<<dim3(256 / 64, (NN + 63) / 64), 256, 0, stream>>>(x[g], W1, bufH, NN, 256, 128);
        hipMemsetAsync(bufA, 0, (size_t)NN * 256 * 4, stream);
        k_scatter<256><<<(Eg + 3) / 4, 256, 0, stream>>>(srcp, dstp, bufH, dinv, bufA, Eg);
        k_final<256><<<(NN * 64 + 255) / 256, 256, 0, stream>>>(bufA, bufH, dinv, b1, bufA, NN);

        // ---- layer 2: h2 = x1 @ W2 ; agg ; z = relu(agg + self + b2)
        sgemm64<<<dim3(128 / 64, (NN + 63) / 64), 256, 0, stream>>>(bufA, W2, bufH, NN, 128, 256);
        hipMemsetAsync(bufA, 0, (size_t)NN * 128 * 4, stream);
        k_scatter<128><<<(Eg + 7) / 8, 256, 0, stream>>>(srcp, dstp, bufH, dinv, bufA, Eg);
        k_final<128><<<(NN * 32 + 255) / 256, 256, 0, stream>>>(bufA, bufH, dinv, b2,
                                                                out + (size_t)g * NN * 128, NN);
    }
}

// Round 4
// 1034.125 us; speedup vs baseline: 8.1857x; 8.1857x over previous
//
#include <hip/hip_runtime.h>

#define NN 50000

// ---------------- degree (int) ----------------
__global__ __launch_bounds__(256) void k_deg(const int* __restrict__ dst, int E,
                                             int* __restrict__ deg) {
    int e = blockIdx.x * 256 + threadIdx.x;
    if (e < E) atomicAdd(&deg[dst[e]], 1);
}

__global__ __launch_bounds__(256) void k_dinv(const int* __restrict__ deg,
                                              float* __restrict__ dinv, int n) {
    int i = blockIdx.x * 256 + threadIdx.x;
    if (i < n) dinv[i] = rsqrtf((float)deg[i] + 1.0f);  // +1 self-loop
}

// ---------------- exclusive scan over deg -> row_ptr (and cursor copy) ----------------
// single block, 1024 threads, chunked Hillis-Steele. n=50000 -> 49 chunks.
__global__ __launch_bounds__(1024) void k_scan(const int* __restrict__ deg,
                                               int* __restrict__ row_ptr,
                                               int* __restrict__ cursor, int n) {
    __shared__ int smem[1024];
    __shared__ int carry;
    const int tid = threadIdx.x;
    if (tid == 0) carry = 0;
    __syncthreads();
    for (int base = 0; base < n; base += 1024) {
        int i = base + tid;
        int v = (i < n) ? deg[i] : 0;
        smem[tid] = v;
        __syncthreads();
#pragma unroll
        for (int off = 1; off < 1024; off <<= 1) {
            int t = (tid >= off) ? smem[tid - off] : 0;
            __syncthreads();
            smem[tid] += t;
            __syncthreads();
        }
        if (i < n) {
            int excl = carry + smem[tid] - v;
            row_ptr[i] = excl;
            cursor[i] = excl;
        }
        __syncthreads();
        if (tid == 0) carry += smem[1023];
        __syncthreads();
    }
    if (tid == 0) row_ptr[n] = carry;
}

// ---------------- bin edges by dst: fill sorted src + precomputed norm ----------------
__global__ __launch_bounds__(256) void k_bin(const int* __restrict__ src,
                                             const int* __restrict__ dst,
                                             const float* __restrict__ dinv,
                                             int* __restrict__ cursor,
                                             int* __restrict__ e_src,
                                             float* __restrict__ e_norm, int E) {
    int e = blockIdx.x * 256 + threadIdx.x;
    if (e >= E) return;
    int s = src[e], d = dst[e];
    int slot = atomicAdd(&cursor[d], 1);
    e_src[slot] = s;
    e_norm[slot] = dinv[s] * dinv[d];
}

// ---------------- f32 tiled GEMM: C[M,N] = A[M,K] * B[K,N] ----------------
__global__ __launch_bounds__(256) void sgemm64(const float* __restrict__ A,
                                               const float* __restrict__ B,
                                               float* __restrict__ C,
                                               int M, int N, int K) {
    __shared__ float As[16][64];  // transposed: As[k][m]
    __shared__ float Bs[16][64];
    const int tid = threadIdx.x;
    const int bm = blockIdx.y * 64;
    const int bn = blockIdx.x * 64;
    const int ty = tid >> 4, tx = tid & 15;
    const int arow = tid >> 2, akk = (tid & 3) * 4;
    const int brow = tid >> 4, bcol = (tid & 15) * 4;

    float acc[4][4] = {};

    for (int k0 = 0; k0 < K; k0 += 16) {
        float4 av = make_float4(0.f, 0.f, 0.f, 0.f);
        int gr = bm + arow;
        if (gr < M) av = *(const float4*)&A[(size_t)gr * K + k0 + akk];
        As[akk + 0][arow] = av.x;
        As[akk + 1][arow] = av.y;
        As[akk + 2][arow] = av.z;
        As[akk + 3][arow] = av.w;
        *(float4*)&Bs[brow][bcol] = *(const float4*)&B[(size_t)(k0 + brow) * N + bn + bcol];
        __syncthreads();
#pragma unroll
        for (int kk = 0; kk < 16; ++kk) {
            float4 a = *(const float4*)&As[kk][ty * 4];
            float4 b = *(const float4*)&Bs[kk][tx * 4];
            float ar[4] = {a.x, a.y, a.z, a.w};
            float br[4] = {b.x, b.y, b.z, b.w};
#pragma unroll
            for (int i = 0; i < 4; ++i)
#pragma unroll
                for (int j = 0; j < 4; ++j) acc[i][j] += ar[i] * br[j];
        }
        __syncthreads();
    }
#pragma unroll
    for (int i = 0; i < 4; ++i) {
        int gr = bm + ty * 4 + i;
        if (gr < M)
            *(float4*)&C[(size_t)gr * N + bn + tx * 4] =
                make_float4(acc[i][0], acc[i][1], acc[i][2], acc[i][3]);
    }
}

// ---------------- CSR aggregate + self-loop + bias + ReLU (fused) ----------------
// One 64-lane wave per destination node. C=256: float4/lane; C=128: float2/lane.
template <int C>
__global__ __launch_bounds__(256) void k_aggregate(const int* __restrict__ row_ptr,
                                                   const int* __restrict__ e_src,
                                                   const float* __restrict__ e_norm,
                                                   const float* __restrict__ h,
                                                   const float* __restrict__ dinv,
                                                   const float* __restrict__ bias,
                                                   float* __restrict__ out, int n) {
    constexpr int VPL = C / 64;  // floats per lane
    const int node = (blockIdx.x * 256 + threadIdx.x) / 64;
    const int lane = threadIdx.x & 63;
    if (node >= n) return;
    const int beg = row_ptr[node], end = row_ptr[node + 1];

    float acc[VPL] = {};
    int e = beg;
    // 2-edge unroll for memory-level parallelism
    for (; e + 1 < end; e += 2) {
        const int s0 = e_src[e], s1 = e_src[e + 1];
        const float n0 = e_norm[e], n1 = e_norm[e + 1];
        if constexpr (VPL == 4) {
            float4 v0 = *(const float4*)&h[(size_t)s0 * C + lane * 4];
            float4 v1 = *(const float4*)&h[(size_t)s1 * C + lane * 4];
            acc[0] += v0.x * n0; acc[1] += v0.y * n0; acc[2] += v0.z * n0; acc[3] += v0.w * n0;
            acc[0] += v1.x * n1; acc[1] += v1.y * n1; acc[2] += v1.z * n1; acc[3] += v1.w * n1;
        } else {
            float2 v0 = *(const float2*)&h[(size_t)s0 * C + lane * 2];
            float2 v1 = *(const float2*)&h[(size_t)s1 * C + lane * 2];
            acc[0] += v0.x * n0; acc[1] += v0.y * n0;
            acc[0] += v1.x * n1; acc[1] += v1.y * n1;
        }
    }
    if (e < end) {
        const int s = e_src[e];
        const float nr = e_norm[e];
        if constexpr (VPL == 4) {
            float4 v = *(const float4*)&h[(size_t)s * C + lane * 4];
            acc[0] += v.x * nr; acc[1] += v.y * nr; acc[2] += v.z * nr; acc[3] += v.w * nr;
        } else {
            float2 v = *(const float2*)&h[(size_t)s * C + lane * 2];
            acc[0] += v.x * nr; acc[1] += v.y * nr;
        }
    }

    const float di = dinv[node];
    const float d2 = di * di;
    const float* hp = &h[(size_t)node * C + lane * VPL];
    const float* bp = &bias[lane * VPL];
    float* op = &out[(size_t)node * C + lane * VPL];
    if constexpr (VPL == 4) {
        float4 hv = *(const float4*)hp;
        float4 bv = *(const float4*)bp;
        float4 r;
        r.x = fmaxf(acc[0] + hv.x * d2 + bv.x, 0.f);
        r.y = fmaxf(acc[1] + hv.y * d2 + bv.y, 0.f);
        r.z = fmaxf(acc[2] + hv.z * d2 + bv.z, 0.f);
        r.w = fmaxf(acc[3] + hv.w * d2 + bv.w, 0.f);
        *(float4*)op = r;
    } else {
        float2 hv = *(const float2*)hp;
        float2 bv = *(const float2*)bp;
        float2 r;
        r.x = fmaxf(acc[0] + hv.x * d2 + bv.x, 0.f);
        r.y = fmaxf(acc[1] + hv.y * d2 + bv.y, 0.f);
        *(float2*)op = r;
    }
}

extern "C" void kernel_launch(void* const* d_in, const int* in_sizes, int n_in,
                              void* d_out, int out_size, void* d_ws, size_t ws_size,
                              hipStream_t stream) {
    const float* x[2] = {(const float*)d_in[0], (const float*)d_in[2]};
    const int* eidx[2] = {(const int*)d_in[1], (const int*)d_in[3]};
    const int E[2] = {in_sizes[1] / 2, in_sizes[3] / 2};
    const float* W1 = (const float*)d_in[4];
    const float* b1 = (const float*)d_in[5];
    const float* W2 = (const float*)d_in[6];
    const float* b2 = (const float*)d_in[7];
    float* out = (float*)d_out;

    const int Emax = (E[0] > E[1]) ? E[0] : E[1];
    char* ws = (char*)d_ws;
    size_t off = 0;
    float* bufH = (float*)(ws + off); off += (size_t)NN * 256 * 4;   // h (x@W)
    float* bufX = (float*)(ws + off); off += (size_t)NN * 256 * 4;   // layer-1 activation
    int* deg    = (int*)(ws + off);   off += (size_t)NN * 4;
    float* dinv = (float*)(ws + off); off += (size_t)NN * 4;
    int* rowp   = (int*)(ws + off);   off += (size_t)(NN + 1) * 4;
    int* cursor = (int*)(ws + off);   off += (size_t)NN * 4;
    int* e_src  = (int*)(ws + off);   off += (size_t)Emax * 4;
    float* e_nrm= (float*)(ws + off); off += (size_t)Emax * 4;

    for (int g = 0; g < 2; ++g) {
        const int Eg = E[g];
        const int* srcp = eidx[g];
        const int* dstp = eidx[g] + Eg;

        // ---- CSR build (once per graph, reused by both layers)
        hipMemsetAsync(deg, 0, NN * sizeof(int), stream);
        k_deg<<<(Eg + 255) / 256, 256, 0, stream>>>(dstp, Eg, deg);
        k_dinv<<<(NN + 255) / 256, 256, 0, stream>>>(deg, dinv, NN);
        k_scan<<<1, 1024, 0, stream>>>(deg, rowp, cursor, NN);
        k_bin<<<(Eg + 255) / 256, 256, 0, stream>>>(srcp, dstp, dinv, cursor, e_src, e_nrm, Eg);

        // ---- layer 1: h = x @ W1 ; fused aggregate+self+bias+relu -> bufX
        sgemm64<<<dim3(256 / 64, (NN + 63) / 64), 256, 0, stream>>>(x[g], W1, bufH, NN, 256, 128);
        k_aggregate<256><<<(NN + 3) / 4, 256, 0, stream>>>(rowp, e_src, e_nrm, bufH, dinv, b1,
                                                           bufX, NN);

        // ---- layer 2: h2 = bufX @ W2 ; fused aggregate -> out
        sgemm64<<<dim3(128 / 64, (NN + 63) / 64), 256, 0, stream>>>(bufX, W2, bufH, NN, 128, 256);
        k_aggregate<128><<<(NN + 3) / 4, 256, 0, stream>>>(rowp, e_src, e_nrm, bufH, dinv, b2,
                                                           out + (size_t)g * NN * 128, NN);
    }
}

// Round 5
// 813.888 us; speedup vs baseline: 10.4007x; 1.2706x over previous
//
#include <hip/hip_runtime.h>

#define NN 50000

// ---------------- degree (int) ----------------
__global__ __launch_bounds__(256) void k_deg(const int* __restrict__ dst, int E,
                                             int* __restrict__ deg) {
    int e = blockIdx.x * 256 + threadIdx.x;
    if (e < E) atomicAdd(&deg[dst[e]], 1);
}

__global__ __launch_bounds__(256) void k_dinv(const int* __restrict__ deg,
                                              float* __restrict__ dinv, int n) {
    int i = blockIdx.x * 256 + threadIdx.x;
    if (i < n) dinv[i] = rsqrtf((float)deg[i] + 1.0f);  // +1 self-loop
}

// ---------------- exclusive scan over deg -> row_ptr (+ cursor copy) ----------------
// single block, 1024 threads = 16 waves; per-wave shuffle scan, 3 barriers/chunk.
__global__ __launch_bounds__(1024) void k_scan(const int* __restrict__ deg,
                                               int* __restrict__ row_ptr,
                                               int* __restrict__ cursor, int n) {
    __shared__ int wsum[16];
    __shared__ int carry_s;
    const int tid = threadIdx.x;
    const int wid = tid >> 6, lane = tid & 63;
    if (tid == 0) carry_s = 0;
    __syncthreads();
    for (int base = 0; base < n; base += 1024) {
        const int i = base + tid;
        const int v = (i < n) ? deg[i] : 0;
        // inclusive scan within wave
        int s = v;
#pragma unroll
        for (int off = 1; off < 64; off <<= 1) {
            int t = __shfl_up(s, off, 64);
            if (lane >= off) s += t;
        }
        if (lane == 63) wsum[wid] = s;
        __syncthreads();  // B1: wsum ready
        if (wid == 0) {
            int ws = (lane < 16) ? wsum[lane] : 0;
#pragma unroll
            for (int off = 1; off < 16; off <<= 1) {
                int t = __shfl_up(ws, off, 64);
                if (lane >= off) ws += t;
            }
            if (lane < 16) wsum[lane] = ws;  // inclusive over waves
        }
        __syncthreads();  // B2: scanned wsum ready
        const int waveoff = (wid == 0) ? 0 : wsum[wid - 1];
        const int carry = carry_s;
        const int total = wsum[15];
        if (i < n) {
            int excl = carry + waveoff + s - v;
            row_ptr[i] = excl;
            cursor[i] = excl;
        }
        __syncthreads();  // B3: all reads of carry_s/wsum done
        if (tid == 0) carry_s = carry + total;
    }
    if (tid == 0) row_ptr[n] = carry_s;
}

// ---------------- bin edges by dst: sorted src + precomputed norm ----------------
__global__ __launch_bounds__(256) void k_bin(const int* __restrict__ src,
                                             const int* __restrict__ dst,
                                             const float* __restrict__ dinv,
                                             int* __restrict__ cursor,
                                             int* __restrict__ e_src,
                                             float* __restrict__ e_norm, int E) {
    int e = blockIdx.x * 256 + threadIdx.x;
    if (e >= E) return;
    int s = src[e], d = dst[e];
    int slot = atomicAdd(&cursor[d], 1);
    e_src[slot] = s;
    e_norm[slot] = dinv[s] * dinv[d];
}

// ---------------- f32 tiled GEMM: C[M,N] = A[M,K]*B[K,N] (+ optional bias+relu) ----
template <bool EPI>
__global__ __launch_bounds__(256) void sgemm64(const float* __restrict__ A,
                                               const float* __restrict__ B,
                                               const float* __restrict__ bias,
                                               float* __restrict__ C,
                                               int M, int N, int K) {
    __shared__ float As[16][64];  // transposed: As[k][m]
    __shared__ float Bs[16][64];
    const int tid = threadIdx.x;
    const int bm = blockIdx.y * 64;
    const int bn = blockIdx.x * 64;
    const int ty = tid >> 4, tx = tid & 15;
    const int arow = tid >> 2, akk = (tid & 3) * 4;
    const int brow = tid >> 4, bcol = (tid & 15) * 4;

    float acc[4][4] = {};

    for (int k0 = 0; k0 < K; k0 += 16) {
        float4 av = make_float4(0.f, 0.f, 0.f, 0.f);
        int gr = bm + arow;
        if (gr < M) av = *(const float4*)&A[(size_t)gr * K + k0 + akk];
        As[akk + 0][arow] = av.x;
        As[akk + 1][arow] = av.y;
        As[akk + 2][arow] = av.z;
        As[akk + 3][arow] = av.w;
        *(float4*)&Bs[brow][bcol] = *(const float4*)&B[(size_t)(k0 + brow) * N + bn + bcol];
        __syncthreads();
#pragma unroll
        for (int kk = 0; kk < 16; ++kk) {
            float4 a = *(const float4*)&As[kk][ty * 4];
            float4 b = *(const float4*)&Bs[kk][tx * 4];
            float ar[4] = {a.x, a.y, a.z, a.w};
            float br[4] = {b.x, b.y, b.z, b.w};
#pragma unroll
            for (int i = 0; i < 4; ++i)
#pragma unroll
                for (int j = 0; j < 4; ++j) acc[i][j] += ar[i] * br[j];
        }
        __syncthreads();
    }
    float4 bv = make_float4(0.f, 0.f, 0.f, 0.f);
    if (EPI) bv = *(const float4*)&bias[bn + tx * 4];
#pragma unroll
    for (int i = 0; i < 4; ++i) {
        int gr = bm + ty * 4 + i;
        if (gr < M) {
            float4 r = make_float4(acc[i][0], acc[i][1], acc[i][2], acc[i][3]);
            if (EPI) {
                r.x = fmaxf(r.x + bv.x, 0.f);
                r.y = fmaxf(r.y + bv.y, 0.f);
                r.z = fmaxf(r.z + bv.z, 0.f);
                r.w = fmaxf(r.w + bv.w, 0.f);
            }
            *(float4*)&C[(size_t)gr * N + bn + tx * 4] = r;
        }
    }
}

// ---------------- CSR aggregate (C=128): out = Â h (+ optional bias+relu) ----------
// Â includes self-loop (dinv^2). One 64-lane wave per node, float2/lane, unroll 4.
template <bool BIAS_RELU>
__global__ __launch_bounds__(256) void k_agg(const int* __restrict__ row_ptr,
                                             const int* __restrict__ e_src,
                                             const float* __restrict__ e_norm,
                                             const float* __restrict__ h,
                                             const float* __restrict__ dinv,
                                             const float* __restrict__ bias,
                                             float* __restrict__ out, int n) {
    constexpr int C = 128;
    const int node = (blockIdx.x * 256 + threadIdx.x) >> 6;
    const int lane = threadIdx.x & 63;
    if (node >= n) return;
    const int beg = row_ptr[node], end = row_ptr[node + 1];

    float a0 = 0.f, a1 = 0.f;
    int e = beg;
    for (; e + 3 < end; e += 4) {
        const int s0 = e_src[e + 0], s1 = e_src[e + 1];
        const int s2 = e_src[e + 2], s3 = e_src[e + 3];
        const float n0 = e_norm[e + 0], n1 = e_norm[e + 1];
        const float n2 = e_norm[e + 2], n3 = e_norm[e + 3];
        const float2 v0 = *(const float2*)&h[(size_t)s0 * C + lane * 2];
        const float2 v1 = *(const float2*)&h[(size_t)s1 * C + lane * 2];
        const float2 v2 = *(const float2*)&h[(size_t)s2 * C + lane * 2];
        const float2 v3 = *(const float2*)&h[(size_t)s3 * C + lane * 2];
        a0 += v0.x * n0 + v1.x * n1 + v2.x * n2 + v3.x * n3;
        a1 += v0.y * n0 + v1.y * n1 + v2.y * n2 + v3.y * n3;
    }
    for (; e < end; ++e) {
        const int s = e_src[e];
        const float nr = e_norm[e];
        const float2 v = *(const float2*)&h[(size_t)s * C + lane * 2];
        a0 += v.x * nr;
        a1 += v.y * nr;
    }
    // self-loop
    const float di = dinv[node];
    const float d2 = di * di;
    const float2 hv = *(const float2*)&h[(size_t)node * C + lane * 2];
    a0 += hv.x * d2;
    a1 += hv.y * d2;
    if constexpr (BIAS_RELU) {
        const float2 bv = *(const float2*)&bias[lane * 2];
        a0 = fmaxf(a0 + bv.x, 0.f);
        a1 = fmaxf(a1 + bv.y, 0.f);
    }
    *(float2*)&out[(size_t)node * C + lane * 2] = make_float2(a0, a1);
}

extern "C" void kernel_launch(void* const* d_in, const int* in_sizes, int n_in,
                              void* d_out, int out_size, void* d_ws, size_t ws_size,
                              hipStream_t stream) {
    const float* x[2] = {(const float*)d_in[0], (const float*)d_in[2]};
    const int* eidx[2] = {(const int*)d_in[1], (const int*)d_in[3]};
    const int E[2] = {in_sizes[1] / 2, in_sizes[3] / 2};
    const float* W1 = (const float*)d_in[4];
    const float* b1 = (const float*)d_in[5];
    const float* W2 = (const float*)d_in[6];
    const float* b2 = (const float*)d_in[7];
    float* out = (float*)d_out;

    const int Emax = (E[0] > E[1]) ? E[0] : E[1];
    char* ws = (char*)d_ws;
    size_t off = 0;
    float* bufA = (float*)(ws + off); off += (size_t)NN * 128 * 4;   // aggX, later h2
    float* bufB = (float*)(ws + off); off += (size_t)NN * 256 * 4;   // x1 (layer-1 act)
    int* deg    = (int*)(ws + off);   off += (size_t)NN * 4;
    float* dinv = (float*)(ws + off); off += (size_t)NN * 4;
    int* rowp   = (int*)(ws + off);   off += (size_t)(NN + 1) * 4;
    int* cursor = (int*)(ws + off);   off += (size_t)NN * 4;
    int* e_src  = (int*)(ws + off);   off += (size_t)Emax * 4;
    float* e_nrm= (float*)(ws + off); off += (size_t)Emax * 4;

    for (int g = 0; g < 2; ++g) {
        const int Eg = E[g];
        const int* srcp = eidx[g];
        const int* dstp = eidx[g] + Eg;

        // ---- CSR build (once per graph, reused by both layers)
        hipMemsetAsync(deg, 0, NN * sizeof(int), stream);
        k_deg<<<(Eg + 255) / 256, 256, 0, stream>>>(dstp, Eg, deg);
        k_dinv<<<(NN + 255) / 256, 256, 0, stream>>>(deg, dinv, NN);
        k_scan<<<1, 1024, 0, stream>>>(deg, rowp, cursor, NN);
        k_bin<<<(Eg + 255) / 256, 256, 0, stream>>>(srcp, dstp, dinv, cursor, e_src, e_nrm, Eg);

        // ---- layer 1 (aggregate-first): aggX = Â x ; x1 = relu(aggX @ W1 + b1)
        k_agg<false><<<(NN + 3) / 4, 256, 0, stream>>>(rowp, e_src, e_nrm, x[g], dinv, nullptr,
                                                       bufA, NN);
        sgemm64<true><<<dim3(256 / 64, (NN + 63) / 64), 256, 0, stream>>>(bufA, W1, b1, bufB,
                                                                          NN, 256, 128);

        // ---- layer 2 (aggregate-last): h2 = x1 @ W2 ; out = relu(Â h2 + b2)
        sgemm64<false><<<dim3(128 / 64, (NN + 63) / 64), 256, 0, stream>>>(bufB, W2, nullptr,
                                                                           bufA, NN, 128, 256);
        k_agg<true><<<(NN + 3) / 4, 256, 0, stream>>>(rowp, e_src, e_nrm, bufA, dinv, b2,
                                                      out + (size_t)g * NN * 128, NN);
    }
}

// Round 8
// 676.280 us; speedup vs baseline: 12.5171x; 1.2035x over previous
//
#include <hip/hip_runtime.h>

#define NN 50000

typedef __attribute__((ext_vector_type(8))) short s16x8;
typedef __attribute__((ext_vector_type(8))) unsigned short u16x8;
typedef __attribute__((ext_vector_type(4))) float f32x4;

__device__ inline unsigned short f2bf(float f) {
    unsigned u = __float_as_uint(f);
    u += 0x7fff + ((u >> 16) & 1);  // RNE
    return (unsigned short)(u >> 16);
}
__device__ inline float bf2f(unsigned short h) { return __uint_as_float((unsigned)h << 16); }

// ---------------- degree (int) ----------------
__global__ __launch_bounds__(256) void k_deg(const int* __restrict__ dst, int E,
                                             int* __restrict__ deg) {
    int e = blockIdx.x * 256 + threadIdx.x;
    if (e < E) atomicAdd(&deg[dst[e]], 1);
}

// ---------------- block sums of deg (+ fused dinv) ----------------
__global__ __launch_bounds__(1024) void k_bsum_dinv(const int* __restrict__ deg,
                                                    float* __restrict__ dinv,
                                                    int* __restrict__ bsum, int n) {
    const int tid = threadIdx.x;
    const int i = blockIdx.x * 1024 + tid;
    int v = 0;
    if (i < n) {
        v = deg[i];
        dinv[i] = rsqrtf((float)v + 1.0f);  // +1 self-loop
    }
    int s = v;
#pragma unroll
    for (int off = 32; off; off >>= 1) s += __shfl_down(s, off, 64);
    __shared__ int ws[16];
    if ((tid & 63) == 0) ws[tid >> 6] = s;
    __syncthreads();
    if (tid < 16) {
        int t = ws[tid];
#pragma unroll
        for (int off = 8; off; off >>= 1) t += __shfl_down(t, off, 16);
        if (tid == 0) bsum[blockIdx.x] = t;
    }
}

// ---------------- scan of <=64 block sums -> block offsets ----------------
__global__ __launch_bounds__(64) void k_pscan(const int* __restrict__ bsum,
                                              int* __restrict__ boff, int nb,
                                              int* __restrict__ rowp_last, int E) {
    const int tid = threadIdx.x;
    int v = (tid < nb) ? bsum[tid] : 0;
    int s = v;
#pragma unroll
    for (int off = 1; off < 64; off <<= 1) {
        int t = __shfl_up(s, off, 64);
        if (tid >= off) s += t;
    }
    if (tid < nb) boff[tid] = s - v;
    if (tid == 0) *rowp_last = E;
}

// ---------------- per-block exclusive scan + offset -> row_ptr & cursor ----------------
__global__ __launch_bounds__(1024) void k_scan2(const int* __restrict__ deg,
                                                const int* __restrict__ boff,
                                                int* __restrict__ rowp,
                                                int* __restrict__ cursor, int n) {
    const int tid = threadIdx.x;
    const int i = blockIdx.x * 1024 + tid;
    const int wid = tid >> 6, lane = tid & 63;
    int v = (i < n) ? deg[i] : 0;
    int s = v;
#pragma unroll
    for (int off = 1; off < 64; off <<= 1) {
        int t = __shfl_up(s, off, 64);
        if (lane >= off) s += t;
    }
    __shared__ int ws[16];
    if (lane == 63) ws[wid] = s;
    __syncthreads();
    if (wid == 0) {
        int t = (lane < 16) ? ws[lane] : 0;
#pragma unroll
        for (int off = 1; off < 16; off <<= 1) {
            int u = __shfl_up(t, off, 64);
            if (lane >= off) t += u;
        }
        if (lane < 16) ws[lane] = t;
    }
    __syncthreads();
    const int woff = wid ? ws[wid - 1] : 0;
    if (i < n) {
        int excl = boff[blockIdx.x] + woff + s - v;
        rowp[i] = excl;
        cursor[i] = excl;
    }
}

// ---------------- bin edges by dst: sorted src + precomputed norm ----------------
__global__ __launch_bounds__(256) void k_bin(const int* __restrict__ src,
                                             const int* __restrict__ dst,
                                             const float* __restrict__ dinv,
                                             int* __restrict__ cursor,
                                             int* __restrict__ e_src,
                                             float* __restrict__ e_norm, int E) {
    int e = blockIdx.x * 256 + threadIdx.x;
    if (e >= E) return;
    int s = src[e], d = dst[e];
    int slot = atomicAdd(&cursor[d], 1);
    e_src[slot] = s;
    e_norm[slot] = dinv[s] * dinv[d];
}

// ---------------- weight convert: W[K][N] f32 -> Wh/Wl [N][K] bf16, k-permuted ----------
// pos within each 32-k block matches the MFMA fragment staging order used in mgemm.
__global__ __launch_bounds__(256) void k_wcvt(const float* __restrict__ W,
                                              unsigned short* __restrict__ Wh,
                                              unsigned short* __restrict__ Wl,
                                              int K, int N) {
    int idx = blockIdx.x * 256 + threadIdx.x;
    if (idx >= K * N) return;
    int k = idx / N, n = idx % N;
    float v = W[idx];
    unsigned short h = f2bf(v);
    unsigned short l = f2bf(v - bf2f(h));
    int klo = k & 31;
    int pos = (k & ~31) + ((klo & 15) >> 2) * 8 + ((klo >> 4) & 1) * 4 + (klo & 3);
    Wh[(size_t)n * K + pos] = h;
    Wl[(size_t)n * K + pos] = l;
}

// ---------------- split-bf16 MFMA GEMM: C[M,N] = A[M,K] * W[K,N] (+bias+relu) --------
// A f32 (converted to hi/lo bf16 during LDS staging); W pre-converted [N][K] hi/lo.
// BM=BN=BK=64, 256 threads = 4 waves (2x2), wave tile 32x32, 16x16x32 MFMA, 3 passes.
template <bool EPI>
__global__ __launch_bounds__(256) void mgemm(const float* __restrict__ A,
                                             const unsigned short* __restrict__ Wh,
                                             const unsigned short* __restrict__ Wl,
                                             const float* __restrict__ bias,
                                             float* __restrict__ C,
                                             int M, int N, int K) {
    __shared__ unsigned short Ah[64 * 64], Al[64 * 64];  // [row][64k perm+swz] 8KB each
    __shared__ unsigned short Bh[64 * 64], Bl[64 * 64];  // [col][64k perm+swz]
    const int tid = threadIdx.x;
    const int bm = blockIdx.y * 64;
    const int bn = blockIdx.x * 64;
    const int wid = tid >> 6, lane = tid & 63;
    const int wr = (wid >> 1) * 32, wc = (wid & 1) * 32;
    const int l15 = lane & 15, lg = lane >> 4;

    f32x4 acc[2][2] = {};

    // A staging map: 4 passes, row = p*16 + (tid>>4), f32 k-chunk sk0 = (tid&15)*4
    const int srow = tid >> 4;
    const int sk0 = (tid & 15) * 4;
    const int sb = (sk0 >> 5) * 64 + (((sk0 & 15) >> 2) * 8 + ((sk0 >> 4) & 1) * 4) * 2;
    // B staging map: col = tid>>2, 32-byte chunk at bck
    const int bcol = tid >> 2;
    const int bck = (tid & 3) * 32;

    for (int kt = 0; kt < K; kt += 64) {
        // ---- stage A: f32 -> (hi,lo) bf16, k-permuted, XOR-swizzled
#pragma unroll
        for (int p = 0; p < 4; ++p) {
            const int row = p * 16 + srow;
            const int gr = bm + row;
            float4 v = make_float4(0.f, 0.f, 0.f, 0.f);
            if (gr < M) v = *(const float4*)&A[(size_t)gr * K + kt + sk0];
            const unsigned short h0 = f2bf(v.x), h1 = f2bf(v.y), h2 = f2bf(v.z), h3 = f2bf(v.w);
            const unsigned short l0 = f2bf(v.x - bf2f(h0)), l1 = f2bf(v.y - bf2f(h1));
            const unsigned short l2 = f2bf(v.z - bf2f(h2)), l3 = f2bf(v.w - bf2f(h3));
            const int byte = sb ^ ((row & 7) << 4);
            *(ushort4*)((char*)Ah + row * 128 + byte) = make_ushort4(h0, h1, h2, h3);
            *(ushort4*)((char*)Al + row * 128 + byte) = make_ushort4(l0, l1, l2, l3);
        }
        // ---- stage B: straight bf16 copies (already permuted in Wh/Wl)
        {
            const unsigned short* gh = &Wh[(size_t)(bn + bcol) * K + kt + (bck >> 1)];
            const unsigned short* gl = &Wl[(size_t)(bn + bcol) * K + kt + (bck >> 1)];
            const int byt0 = bck ^ ((bcol & 7) << 4);
            const int byt1 = (bck + 16) ^ ((bcol & 7) << 4);
            *(u16x8*)((char*)Bh + bcol * 128 + byt0) = *(const u16x8*)gh;
            *(u16x8*)((char*)Bh + bcol * 128 + byt1) = *(const u16x8*)(gh + 8);
            *(u16x8*)((char*)Bl + bcol * 128 + byt0) = *(const u16x8*)gl;
            *(u16x8*)((char*)Bl + bcol * 128 + byt1) = *(const u16x8*)(gl + 8);
        }
        __syncthreads();
#pragma unroll
        for (int kk = 0; kk < 2; ++kk) {
            s16x8 ah[2], al[2], bh[2], bl[2];
#pragma unroll
            for (int rf = 0; rf < 2; ++rf) {
                const int row = wr + rf * 16 + l15;
                const int byte = (kk * 64 + lg * 16) ^ ((row & 7) << 4);
                ah[rf] = *(const s16x8*)((const char*)Ah + row * 128 + byte);
                al[rf] = *(const s16x8*)((const char*)Al + row * 128 + byte);
            }
#pragma unroll
            for (int cf = 0; cf < 2; ++cf) {
                const int col = wc + cf * 16 + l15;
                const int byte = (kk * 64 + lg * 16) ^ ((col & 7) << 4);
                bh[cf] = *(const s16x8*)((const char*)Bh + col * 128 + byte);
                bl[cf] = *(const s16x8*)((const char*)Bl + col * 128 + byte);
            }
#pragma unroll
            for (int rf = 0; rf < 2; ++rf)
#pragma unroll
                for (int cf = 0; cf < 2; ++cf) {
                    acc[rf][cf] = __builtin_amdgcn_mfma_f32_16x16x32_bf16(ah[rf], bh[cf],
                                                                          acc[rf][cf], 0, 0, 0);
                    acc[rf][cf] = __builtin_amdgcn_mfma_f32_16x16x32_bf16(ah[rf], bl[cf],
                                                                          acc[rf][cf], 0, 0, 0);
                    acc[rf][cf] = __builtin_amdgcn_mfma_f32_16x16x32_bf16(al[rf], bh[cf],
                                                                          acc[rf][cf], 0, 0, 0);
                }
        }
        __syncthreads();
    }
    // ---- epilogue: C/D layout col=lane&15, row=(lane>>4)*4+reg (m89-verified)
#pragma unroll
    for (int rf = 0; rf < 2; ++rf)
#pragma unroll
        for (int cf = 0; cf < 2; ++cf) {
            const int col = bn + wc + cf * 16 + l15;
            const float bv = EPI ? bias[col] : 0.f;
#pragma unroll
            for (int r = 0; r < 4; ++r) {
                const int gr = bm + wr + rf * 16 + lg * 4 + r;
                if (gr < M) {
                    float v = acc[rf][cf][r];
                    if (EPI) v = fmaxf(v + bv, 0.f);
                    C[(size_t)gr * N + col] = v;
                }
            }
        }
}

// ---------------- CSR aggregate (C=128): out = Â h (+ optional bias+relu) ----------
template <bool BIAS_RELU>
__global__ __launch_bounds__(256) void k_agg(const int* __restrict__ row_ptr,
                                             const int* __restrict__ e_src,
                                             const float* __restrict__ e_norm,
                                             const float* __restrict__ h,
                                             const float* __restrict__ dinv,
                                             const float* __restrict__ bias,
                                             float* __restrict__ out, int n) {
    constexpr int C = 128;
    const int node = (blockIdx.x * 256 + threadIdx.x) >> 6;
    const int lane = threadIdx.x & 63;
    if (node >= n) return;
    const int beg = row_ptr[node], end = row_ptr[node + 1];

    float a0 = 0.f, a1 = 0.f;
    int e = beg;
    for (; e + 3 < end; e += 4) {
        const int s0 = e_src[e + 0], s1 = e_src[e + 1];
        const int s2 = e_src[e + 2], s3 = e_src[e + 3];
        const float n0 = e_norm[e + 0], n1 = e_norm[e + 1];
        const float n2 = e_norm[e + 2], n3 = e_norm[e + 3];
        const float2 v0 = *(const float2*)&h[(size_t)s0 * C + lane * 2];
        const float2 v1 = *(const float2*)&h[(size_t)s1 * C + lane * 2];
        const float2 v2 = *(const float2*)&h[(size_t)s2 * C + lane * 2];
        const float2 v3 = *(const float2*)&h[(size_t)s3 * C + lane * 2];
        a0 += v0.x * n0 + v1.x * n1 + v2.x * n2 + v3.x * n3;
        a1 += v0.y * n0 + v1.y * n1 + v2.y * n2 + v3.y * n3;
    }
    for (; e < end; ++e) {
        const int s = e_src[e];
        const float nr = e_norm[e];
        const float2 v = *(const float2*)&h[(size_t)s * C + lane * 2];
        a0 += v.x * nr;
        a1 += v.y * nr;
    }
    const float di = dinv[node];
    const float d2 = di * di;
    const float2 hv = *(const float2*)&h[(size_t)node * C + lane * 2];
    a0 += hv.x * d2;
    a1 += hv.y * d2;
    if constexpr (BIAS_RELU) {
        const float2 bv = *(const float2*)&bias[lane * 2];
        a0 = fmaxf(a0 + bv.x, 0.f);
        a1 = fmaxf(a1 + bv.y, 0.f);
    }
    *(float2*)&out[(size_t)node * C + lane * 2] = make_float2(a0, a1);
}

extern "C" void kernel_launch(void* const* d_in, const int* in_sizes, int n_in,
                              void* d_out, int out_size, void* d_ws, size_t ws_size,
                              hipStream_t stream) {
    const float* x[2] = {(const float*)d_in[0], (const float*)d_in[2]};
    const int* eidx[2] = {(const int*)d_in[1], (const int*)d_in[3]};
    const int E[2] = {in_sizes[1] / 2, in_sizes[3] / 2};
    const float* W1 = (const float*)d_in[4];
    const float* b1 = (const float*)d_in[5];
    const float* W2 = (const float*)d_in[6];
    const float* b2 = (const float*)d_in[7];
    float* out = (float*)d_out;

    const int Emax = (E[0] > E[1]) ? E[0] : E[1];
    char* ws = (char*)d_ws;
    size_t off = 0;
    auto alloc = [&](size_t bytes) -> void* {
        void* p = ws + off;
        off = (off + bytes + 255) & ~(size_t)255;
        return p;
    };
    float* bufA = (float*)alloc((size_t)NN * 128 * 4);   // aggX, then h2
    float* bufB = (float*)alloc((size_t)NN * 256 * 4);   // x1
    unsigned short* W1h = (unsigned short*)alloc(128 * 256 * 2);
    unsigned short* W1l = (unsigned short*)alloc(128 * 256 * 2);
    unsigned short* W2h = (unsigned short*)alloc(256 * 128 * 2);
    unsigned short* W2l = (unsigned short*)alloc(256 * 128 * 2);
    int* deg = (int*)alloc((size_t)NN * 4);
    float* dinv = (float*)alloc((size_t)NN * 4);
    int* rowp = (int*)alloc((size_t)(NN + 1) * 4);
    int* cursor = (int*)alloc((size_t)NN * 4);
    int* bsum = (int*)alloc(64 * 4);
    int* boff = (int*)alloc(64 * 4);
    int* e_src = (int*)alloc((size_t)Emax * 4);
    float* e_nrm = (float*)alloc((size_t)Emax * 4);

    const int NB = (NN + 1023) / 1024;  // 49

    // weights: convert+transpose+permute once per call
    k_wcvt<<<(128 * 256 + 255) / 256, 256, 0, stream>>>(W1, W1h, W1l, 128, 256);
    k_wcvt<<<(256 * 128 + 255) / 256, 256, 0, stream>>>(W2, W2h, W2l, 256, 128);

    for (int g = 0; g < 2; ++g) {
        const int Eg = E[g];
        const int* srcp = eidx[g];
        const int* dstp = eidx[g] + Eg;

        // ---- CSR build
        hipMemsetAsync(deg, 0, NN * sizeof(int), stream);
        k_deg<<<(Eg + 255) / 256, 256, 0, stream>>>(dstp, Eg, deg);
        k_bsum_dinv<<<NB, 1024, 0, stream>>>(deg, dinv, bsum, NN);
        k_pscan<<<1, 64, 0, stream>>>(bsum, boff, NB, &rowp[NN], Eg);
        k_scan2<<<NB, 1024, 0, stream>>>(deg, boff, rowp, cursor, NN);
        k_bin<<<(Eg + 255) / 256, 256, 0, stream>>>(srcp, dstp, dinv, cursor, e_src, e_nrm, Eg);

        // ---- layer 1 (aggregate-first): aggX = Â x ; x1 = relu(aggX @ W1 + b1)
        k_agg<false><<<(NN + 3) / 4, 256, 0, stream>>>(rowp, e_src, e_nrm, x[g], dinv, nullptr,
                                                       bufA, NN);
        mgemm<true><<<dim3(256 / 64, (NN + 63) / 64), 256, 0, stream>>>(bufA, W1h, W1l, b1,
                                                                        bufB, NN, 256, 128);

        // ---- layer 2 (aggregate-last): h2 = x1 @ W2 ; out = relu(Â h2 + b2)
        mgemm<false><<<dim3(128 / 64, (NN + 63) / 64), 256, 0, stream>>>(bufB, W2h, W2l, nullptr,
                                                                         bufA, NN, 128, 256);
        k_agg<true><<<(NN + 3) / 4, 256, 0, stream>>>(rowp, e_src, e_nrm, bufA, dinv, b2,
                                                      out + (size_t)g * NN * 128, NN);
    }
}

// Round 13
// 579.727 us; speedup vs baseline: 14.6018x; 1.1665x over previous
//
#include <hip/hip_runtime.h>

#define NN 50000

typedef __attribute__((ext_vector_type(8))) short s16x8;
typedef __attribute__((ext_vector_type(8))) unsigned short u16x8;
typedef __attribute__((ext_vector_type(4))) float f32x4;

__device__ inline unsigned short f2bf(float f) {
    unsigned u = __float_as_uint(f);
    u += 0x7fff + ((u >> 16) & 1);  // RNE
    return (unsigned short)(u >> 16);
}
__device__ inline float bf2f(unsigned short h) { return __uint_as_float((unsigned)h << 16); }

// ---------------- degree (int) ----------------
__global__ __launch_bounds__(256) void k_deg(const int* __restrict__ dst, int E,
                                             int* __restrict__ deg) {
    int e = blockIdx.x * 256 + threadIdx.x;
    if (e < E) atomicAdd(&deg[dst[e]], 1);
}

// ---------------- block sums of deg (+ fused dinv) ----------------
__global__ __launch_bounds__(1024) void k_bsum_dinv(const int* __restrict__ deg,
                                                    float* __restrict__ dinv,
                                                    int* __restrict__ bsum, int n) {
    const int tid = threadIdx.x;
    const int i = blockIdx.x * 1024 + tid;
    int v = 0;
    if (i < n) {
        v = deg[i];
        dinv[i] = rsqrtf((float)v + 1.0f);  // +1 self-loop
    }
    int s = v;
#pragma unroll
    for (int off = 32; off; off >>= 1) s += __shfl_down(s, off, 64);
    __shared__ int ws[16];
    if ((tid & 63) == 0) ws[tid >> 6] = s;
    __syncthreads();
    if (tid < 16) {
        int t = ws[tid];
#pragma unroll
        for (int off = 8; off; off >>= 1) t += __shfl_down(t, off, 16);
        if (tid == 0) bsum[blockIdx.x] = t;
    }
}

// ---------------- scan of <=64 block sums -> block offsets ----------------
__global__ __launch_bounds__(64) void k_pscan(const int* __restrict__ bsum,
                                              int* __restrict__ boff, int nb,
                                              int* __restrict__ rowp_last, int E) {
    const int tid = threadIdx.x;
    int v = (tid < nb) ? bsum[tid] : 0;
    int s = v;
#pragma unroll
    for (int off = 1; off < 64; off <<= 1) {
        int t = __shfl_up(s, off, 64);
        if (tid >= off) s += t;
    }
    if (tid < nb) boff[tid] = s - v;
    if (tid == 0) *rowp_last = E;
}

// ---------------- per-block exclusive scan + offset -> row_ptr & cursor ----------------
__global__ __launch_bounds__(1024) void k_scan2(const int* __restrict__ deg,
                                                const int* __restrict__ boff,
                                                int* __restrict__ rowp,
                                                int* __restrict__ cursor, int n) {
    const int tid = threadIdx.x;
    const int i = blockIdx.x * 1024 + tid;
    const int wid = tid >> 6, lane = tid & 63;
    int v = (i < n) ? deg[i] : 0;
    int s = v;
#pragma unroll
    for (int off = 1; off < 64; off <<= 1) {
        int t = __shfl_up(s, off, 64);
        if (lane >= off) s += t;
    }
    __shared__ int ws[16];
    if (lane == 63) ws[wid] = s;
    __syncthreads();
    if (wid == 0) {
        int t = (lane < 16) ? ws[lane] : 0;
#pragma unroll
        for (int off = 1; off < 16; off <<= 1) {
            int u = __shfl_up(t, off, 64);
            if (lane >= off) t += u;
        }
        if (lane < 16) ws[lane] = t;
    }
    __syncthreads();
    const int woff = wid ? ws[wid - 1] : 0;
    if (i < n) {
        int excl = boff[blockIdx.x] + woff + s - v;
        rowp[i] = excl;
        cursor[i] = excl;
    }
}

// ---------------- bin edges by dst: only ushort src index (norm computed in k_agg) ----
__global__ __launch_bounds__(256) void k_bin(const int* __restrict__ src,
                                             const int* __restrict__ dst,
                                             int* __restrict__ cursor,
                                             unsigned short* __restrict__ e_src, int E) {
    int e = blockIdx.x * 256 + threadIdx.x;
    if (e >= E) return;
    int slot = atomicAdd(&cursor[dst[e]], 1);
    e_src[slot] = (unsigned short)src[e];
}

// ---------------- f32 -> bf16 convert (vectorized) ----------------
__global__ __launch_bounds__(256) void k_cvt_bf(const float* __restrict__ in,
                                                unsigned short* __restrict__ out, int n4) {
    int i = blockIdx.x * 256 + threadIdx.x;
    if (i >= n4) return;
    float4 v = ((const float4*)in)[i];
    ((ushort4*)out)[i] = make_ushort4(f2bf(v.x), f2bf(v.y), f2bf(v.z), f2bf(v.w));
}

// ---------------- weight convert: W[K][N] f32 -> Wh/Wl [N][K] bf16, k-permuted ----------
__global__ __launch_bounds__(256) void k_wcvt(const float* __restrict__ W,
                                              unsigned short* __restrict__ Wh,
                                              unsigned short* __restrict__ Wl,
                                              int K, int N) {
    int idx = blockIdx.x * 256 + threadIdx.x;
    if (idx >= K * N) return;
    int k = idx / N, n = idx % N;
    float v = W[idx];
    unsigned short h = f2bf(v);
    unsigned short l = f2bf(v - bf2f(h));
    int klo = k & 31;
    int pos = (k & ~31) + ((klo & 15) >> 2) * 8 + ((klo >> 4) & 1) * 4 + (klo & 3);
    Wh[(size_t)n * K + pos] = h;
    Wl[(size_t)n * K + pos] = l;
}

// ---------------- split-bf16 MFMA GEMM: C[M,N] = A[M,K] * W[K,N] --------
// EPI: +bias+relu (f32 out). OUTBF: write bf16 instead of f32.
template <bool EPI, bool OUTBF>
__global__ __launch_bounds__(256) void mgemm(const float* __restrict__ A,
                                             const unsigned short* __restrict__ Wh,
                                             const unsigned short* __restrict__ Wl,
                                             const float* __restrict__ bias,
                                             void* __restrict__ Cv,
                                             int M, int N, int K) {
    __shared__ unsigned short Ah[64 * 64], Al[64 * 64];
    __shared__ unsigned short Bh[64 * 64], Bl[64 * 64];
    const int tid = threadIdx.x;
    const int bm = blockIdx.y * 64;
    const int bn = blockIdx.x * 64;
    const int wid = tid >> 6, lane = tid & 63;
    const int wr = (wid >> 1) * 32, wc = (wid & 1) * 32;
    const int l15 = lane & 15, lg = lane >> 4;

    f32x4 acc[2][2] = {};

    const int srow = tid >> 4;
    const int sk0 = (tid & 15) * 4;
    const int sb = (sk0 >> 5) * 64 + (((sk0 & 15) >> 2) * 8 + ((sk0 >> 4) & 1) * 4) * 2;
    const int bcol = tid >> 2;
    const int bck = (tid & 3) * 32;

    for (int kt = 0; kt < K; kt += 64) {
#pragma unroll
        for (int p = 0; p < 4; ++p) {
            const int row = p * 16 + srow;
            const int gr = bm + row;
            float4 v = make_float4(0.f, 0.f, 0.f, 0.f);
            if (gr < M) v = *(const float4*)&A[(size_t)gr * K + kt + sk0];
            const unsigned short h0 = f2bf(v.x), h1 = f2bf(v.y), h2 = f2bf(v.z), h3 = f2bf(v.w);
            const unsigned short l0 = f2bf(v.x - bf2f(h0)), l1 = f2bf(v.y - bf2f(h1));
            const unsigned short l2 = f2bf(v.z - bf2f(h2)), l3 = f2bf(v.w - bf2f(h3));
            const int byte = sb ^ ((row & 7) << 4);
            *(ushort4*)((char*)Ah + row * 128 + byte) = make_ushort4(h0, h1, h2, h3);
            *(ushort4*)((char*)Al + row * 128 + byte) = make_ushort4(l0, l1, l2, l3);
        }
        {
            const unsigned short* gh = &Wh[(size_t)(bn + bcol) * K + kt + (bck >> 1)];
            const unsigned short* gl = &Wl[(size_t)(bn + bcol) * K + kt + (bck >> 1)];
            const int byt0 = bck ^ ((bcol & 7) << 4);
            const int byt1 = (bck + 16) ^ ((bcol & 7) << 4);
            *(u16x8*)((char*)Bh + bcol * 128 + byt0) = *(const u16x8*)gh;
            *(u16x8*)((char*)Bh + bcol * 128 + byt1) = *(const u16x8*)(gh + 8);
            *(u16x8*)((char*)Bl + bcol * 128 + byt0) = *(const u16x8*)gl;
            *(u16x8*)((char*)Bl + bcol * 128 + byt1) = *(const u16x8*)(gl + 8);
        }
        __syncthreads();
#pragma unroll
        for (int kk = 0; kk < 2; ++kk) {
            s16x8 ah[2], al[2], bh[2], bl[2];
#pragma unroll
            for (int rf = 0; rf < 2; ++rf) {
                const int row = wr + rf * 16 + l15;
                const int byte = (kk * 64 + lg * 16) ^ ((row & 7) << 4);
                ah[rf] = *(const s16x8*)((const char*)Ah + row * 128 + byte);
                al[rf] = *(const s16x8*)((const char*)Al + row * 128 + byte);
            }
#pragma unroll
            for (int cf = 0; cf < 2; ++cf) {
                const int col = wc + cf * 16 + l15;
                const int byte = (kk * 64 + lg * 16) ^ ((col & 7) << 4);
                bh[cf] = *(const s16x8*)((const char*)Bh + col * 128 + byte);
                bl[cf] = *(const s16x8*)((const char*)Bl + col * 128 + byte);
            }
#pragma unroll
            for (int rf = 0; rf < 2; ++rf)
#pragma unroll
                for (int cf = 0; cf < 2; ++cf) {
                    acc[rf][cf] = __builtin_amdgcn_mfma_f32_16x16x32_bf16(ah[rf], bh[cf],
                                                                          acc[rf][cf], 0, 0, 0);
                    acc[rf][cf] = __builtin_amdgcn_mfma_f32_16x16x32_bf16(ah[rf], bl[cf],
                                                                          acc[rf][cf], 0, 0, 0);
                    acc[rf][cf] = __builtin_amdgcn_mfma_f32_16x16x32_bf16(al[rf], bh[cf],
                                                                          acc[rf][cf], 0, 0, 0);
                }
        }
        __syncthreads();
    }
    // ---- epilogue: C/D layout col=lane&15, row=(lane>>4)*4+reg (m89-verified)
#pragma unroll
    for (int rf = 0; rf < 2; ++rf)
#pragma unroll
        for (int cf = 0; cf < 2; ++cf) {
            const int col = bn + wc + cf * 16 + l15;
            const float bv = EPI ? bias[col] : 0.f;
#pragma unroll
            for (int r = 0; r < 4; ++r) {
                const int gr = bm + wr + rf * 16 + lg * 4 + r;
                if (gr < M) {
                    float v = acc[rf][cf][r];
                    if (EPI) v = fmaxf(v + bv, 0.f);
                    if constexpr (OUTBF)
                        ((unsigned short*)Cv)[(size_t)gr * N + col] = f2bf(v);
                    else
                        ((float*)Cv)[(size_t)gr * N + col] = v;
                }
            }
        }
}

// ---------------- CSR aggregate over bf16 rows: out_f32 = Â h (+ optional bias+relu) --
// norm computed on the fly from dinv. One 64-lane wave per node, uint (2 bf16) per lane.
template <bool BIAS_RELU>
__global__ __launch_bounds__(256) void k_agg(const int* __restrict__ row_ptr,
                                             const unsigned short* __restrict__ e_src,
                                             const unsigned short* __restrict__ hb,
                                             const float* __restrict__ dinv,
                                             const float* __restrict__ bias,
                                             float* __restrict__ out, int n) {
    constexpr int C = 128;
    const int node = (blockIdx.x * 256 + threadIdx.x) >> 6;
    const int lane = threadIdx.x & 63;
    if (node >= n) return;
    const int beg = row_ptr[node], end = row_ptr[node + 1];
    const float dn = dinv[node];

    float a0 = 0.f, a1 = 0.f;
    int e = beg;
    for (; e + 3 < end; e += 4) {
        const int s0 = e_src[e + 0], s1 = e_src[e + 1];
        const int s2 = e_src[e + 2], s3 = e_src[e + 3];
        const float n0 = dinv[s0] * dn, n1 = dinv[s1] * dn;
        const float n2 = dinv[s2] * dn, n3 = dinv[s3] * dn;
        const unsigned v0 = *(const unsigned*)&hb[(size_t)s0 * C + lane * 2];
        const unsigned v1 = *(const unsigned*)&hb[(size_t)s1 * C + lane * 2];
        const unsigned v2 = *(const unsigned*)&hb[(size_t)s2 * C + lane * 2];
        const unsigned v3 = *(const unsigned*)&hb[(size_t)s3 * C + lane * 2];
        a0 += __uint_as_float(v0 << 16) * n0 + __uint_as_float(v1 << 16) * n1 +
              __uint_as_float(v2 << 16) * n2 + __uint_as_float(v3 << 16) * n3;
        a1 += __uint_as_float(v0 & 0xffff0000u) * n0 + __uint_as_float(v1 & 0xffff0000u) * n1 +
              __uint_as_float(v2 & 0xffff0000u) * n2 + __uint_as_float(v3 & 0xffff0000u) * n3;
    }
    for (; e < end; ++e) {
        const int s = e_src[e];
        const float nr = dinv[s] * dn;
        const unsigned v = *(const unsigned*)&hb[(size_t)s * C + lane * 2];
        a0 += __uint_as_float(v << 16) * nr;
        a1 += __uint_as_float(v & 0xffff0000u) * nr;
    }
    // self-loop
    const unsigned vs = *(const unsigned*)&hb[(size_t)node * C + lane * 2];
    const float d2 = dn * dn;
    a0 += __uint_as_float(vs << 16) * d2;
    a1 += __uint_as_float(vs & 0xffff0000u) * d2;
    if constexpr (BIAS_RELU) {
        const float2 bv = *(const float2*)&bias[lane * 2];
        a0 = fmaxf(a0 + bv.x, 0.f);
        a1 = fmaxf(a1 + bv.y, 0.f);
    }
    *(float2*)&out[(size_t)node * C + lane * 2] = make_float2(a0, a1);
}

extern "C" void kernel_launch(void* const* d_in, const int* in_sizes, int n_in,
                              void* d_out, int out_size, void* d_ws, size_t ws_size,
                              hipStream_t stream) {
    const float* x[2] = {(const float*)d_in[0], (const float*)d_in[2]};
    const int* eidx[2] = {(const int*)d_in[1], (const int*)d_in[3]};
    const int E[2] = {in_sizes[1] / 2, in_sizes[3] / 2};
    const float* W1 = (const float*)d_in[4];
    const float* b1 = (const float*)d_in[5];
    const float* W2 = (const float*)d_in[6];
    const float* b2 = (const float*)d_in[7];
    float* out = (float*)d_out;

    const int Emax = (E[0] > E[1]) ? E[0] : E[1];
    char* ws = (char*)d_ws;
    size_t off = 0;
    auto alloc = [&](size_t bytes) -> void* {
        void* p = ws + off;
        off = (off + bytes + 255) & ~(size_t)255;
        return p;
    };
    float* aggX = (float*)alloc((size_t)NN * 128 * 4);            // Âx (f32, GEMM1 A)
    float* x1 = (float*)alloc((size_t)NN * 256 * 4);              // layer-1 act (f32, GEMM2 A)
    unsigned short* x_bf = (unsigned short*)alloc((size_t)NN * 128 * 2);  // x in bf16 (gather)
    unsigned short* h2_bf = (unsigned short*)alloc((size_t)NN * 128 * 2); // h2 in bf16 (gather)
    unsigned short* W1h = (unsigned short*)alloc(128 * 256 * 2);
    unsigned short* W1l = (unsigned short*)alloc(128 * 256 * 2);
    unsigned short* W2h = (unsigned short*)alloc(256 * 128 * 2);
    unsigned short* W2l = (unsigned short*)alloc(256 * 128 * 2);
    int* deg = (int*)alloc((size_t)NN * 4);
    float* dinv = (float*)alloc((size_t)NN * 4);
    int* rowp = (int*)alloc((size_t)(NN + 1) * 4);
    int* cursor = (int*)alloc((size_t)NN * 4);
    int* bsum = (int*)alloc(64 * 4);
    int* boff = (int*)alloc(64 * 4);
    unsigned short* e_src = (unsigned short*)alloc((size_t)Emax * 2);

    const int NB = (NN + 1023) / 1024;  // 49

    // weights: convert+transpose+permute once per call
    k_wcvt<<<(128 * 256 + 255) / 256, 256, 0, stream>>>(W1, W1h, W1l, 128, 256);
    k_wcvt<<<(256 * 128 + 255) / 256, 256, 0, stream>>>(W2, W2h, W2l, 256, 128);

    for (int g = 0; g < 2; ++g) {
        const int Eg = E[g];
        const int* srcp = eidx[g];
        const int* dstp = eidx[g] + Eg;

        // ---- CSR build + x convert
        hipMemsetAsync(deg, 0, NN * sizeof(int), stream);
        k_cvt_bf<<<(NN * 128 / 4 + 255) / 256, 256, 0, stream>>>(x[g], x_bf, NN * 128 / 4);
        k_deg<<<(Eg + 255) / 256, 256, 0, stream>>>(dstp, Eg, deg);
        k_bsum_dinv<<<NB, 1024, 0, stream>>>(deg, dinv, bsum, NN);
        k_pscan<<<1, 64, 0, stream>>>(bsum, boff, NB, &rowp[NN], Eg);
        k_scan2<<<NB, 1024, 0, stream>>>(deg, boff, rowp, cursor, NN);
        k_bin<<<(Eg + 255) / 256, 256, 0, stream>>>(srcp, dstp, cursor, e_src, Eg);

        // ---- layer 1 (aggregate-first): aggX = Â x ; x1 = relu(aggX @ W1 + b1)
        k_agg<false><<<(NN + 3) / 4, 256, 0, stream>>>(rowp, e_src, x_bf, dinv, nullptr,
                                                       aggX, NN);
        mgemm<true, false><<<dim3(256 / 64, (NN + 63) / 64), 256, 0, stream>>>(
            aggX, W1h, W1l, b1, x1, NN, 256, 128);

        // ---- layer 2 (aggregate-last): h2 = x1 @ W2 (bf16 out); out = relu(Â h2 + b2)
        mgemm<false, true><<<dim3(128 / 64, (NN + 63) / 64), 256, 0, stream>>>(
            x1, W2h, W2l, nullptr, h2_bf, NN, 128, 256);
        k_agg<true><<<(NN + 3) / 4, 256, 0, stream>>>(rowp, e_src, h2_bf, dinv, b2,
                                                      out + (size_t)g * NN * 128, NN);
    }
}

// Round 14
// 534.905 us; speedup vs baseline: 15.8253x; 1.0838x over previous
//
#include <hip/hip_runtime.h>

#define NN 50000

typedef __attribute__((ext_vector_type(8))) short s16x8;
typedef __attribute__((ext_vector_type(8))) unsigned short u16x8;
typedef __attribute__((ext_vector_type(4))) float f32x4;

__device__ inline unsigned short f2bf(float f) {
    unsigned u = __float_as_uint(f);
    u += 0x7fff + ((u >> 16) & 1);  // RNE
    return (unsigned short)(u >> 16);
}
__device__ inline float bf2f(unsigned short h) { return __uint_as_float((unsigned)h << 16); }
__device__ inline float blo(unsigned u) { return __uint_as_float(u << 16); }
__device__ inline float bhi(unsigned u) { return __uint_as_float(u & 0xffff0000u); }

// ---------------- degree (int) ----------------
__global__ __launch_bounds__(256) void k_deg(const int* __restrict__ dst, int E,
                                             int* __restrict__ deg) {
    int e = blockIdx.x * 256 + threadIdx.x;
    if (e < E) atomicAdd(&deg[dst[e]], 1);
}

// ---------------- block sums of deg (+ fused dinv) ----------------
__global__ __launch_bounds__(1024) void k_bsum_dinv(const int* __restrict__ deg,
                                                    float* __restrict__ dinv,
                                                    int* __restrict__ bsum, int n) {
    const int tid = threadIdx.x;
    const int i = blockIdx.x * 1024 + tid;
    int v = 0;
    if (i < n) {
        v = deg[i];
        dinv[i] = rsqrtf((float)v + 1.0f);  // +1 self-loop
    }
    int s = v;
#pragma unroll
    for (int off = 32; off; off >>= 1) s += __shfl_down(s, off, 64);
    __shared__ int ws[16];
    if ((tid & 63) == 0) ws[tid >> 6] = s;
    __syncthreads();
    if (tid < 16) {
        int t = ws[tid];
#pragma unroll
        for (int off = 8; off; off >>= 1) t += __shfl_down(t, off, 16);
        if (tid == 0) bsum[blockIdx.x] = t;
    }
}

// ---------------- scan of <=64 block sums -> block offsets ----------------
__global__ __launch_bounds__(64) void k_pscan(const int* __restrict__ bsum,
                                              int* __restrict__ boff, int nb,
                                              int* __restrict__ rowp_last, int E) {
    const int tid = threadIdx.x;
    int v = (tid < nb) ? bsum[tid] : 0;
    int s = v;
#pragma unroll
    for (int off = 1; off < 64; off <<= 1) {
        int t = __shfl_up(s, off, 64);
        if (tid >= off) s += t;
    }
    if (tid < nb) boff[tid] = s - v;
    if (tid == 0) *rowp_last = E;
}

// ---------------- per-block exclusive scan + offset -> row_ptr & cursor ----------------
__global__ __launch_bounds__(1024) void k_scan2(const int* __restrict__ deg,
                                                const int* __restrict__ boff,
                                                int* __restrict__ rowp,
                                                int* __restrict__ cursor, int n) {
    const int tid = threadIdx.x;
    const int i = blockIdx.x * 1024 + tid;
    const int wid = tid >> 6, lane = tid & 63;
    int v = (i < n) ? deg[i] : 0;
    int s = v;
#pragma unroll
    for (int off = 1; off < 64; off <<= 1) {
        int t = __shfl_up(s, off, 64);
        if (lane >= off) s += t;
    }
    __shared__ int ws[16];
    if (lane == 63) ws[wid] = s;
    __syncthreads();
    if (wid == 0) {
        int t = (lane < 16) ? ws[lane] : 0;
#pragma unroll
        for (int off = 1; off < 16; off <<= 1) {
            int u = __shfl_up(t, off, 64);
            if (lane >= off) t += u;
        }
        if (lane < 16) ws[lane] = t;
    }
    __syncthreads();
    const int woff = wid ? ws[wid - 1] : 0;
    if (i < n) {
        int excl = boff[blockIdx.x] + woff + s - v;
        rowp[i] = excl;
        cursor[i] = excl;
    }
}

// ---------------- bin edges by dst: only ushort src index ----------------
__global__ __launch_bounds__(256) void k_bin(const int* __restrict__ src,
                                             const int* __restrict__ dst,
                                             int* __restrict__ cursor,
                                             unsigned short* __restrict__ e_src, int E) {
    int e = blockIdx.x * 256 + threadIdx.x;
    if (e >= E) return;
    int slot = atomicAdd(&cursor[dst[e]], 1);
    e_src[slot] = (unsigned short)src[e];
}

// ---------------- f32 -> bf16 convert (vectorized) ----------------
__global__ __launch_bounds__(256) void k_cvt_bf(const float* __restrict__ in,
                                                unsigned short* __restrict__ out, int n4) {
    int i = blockIdx.x * 256 + threadIdx.x;
    if (i >= n4) return;
    float4 v = ((const float4*)in)[i];
    ((ushort4*)out)[i] = make_ushort4(f2bf(v.x), f2bf(v.y), f2bf(v.z), f2bf(v.w));
}

// ---------------- weight convert: W[K][N] f32 -> Wh/Wl [N][K] bf16, k-permuted ----------
__global__ __launch_bounds__(256) void k_wcvt(const float* __restrict__ W,
                                              unsigned short* __restrict__ Wh,
                                              unsigned short* __restrict__ Wl,
                                              int K, int N) {
    int idx = blockIdx.x * 256 + threadIdx.x;
    if (idx >= K * N) return;
    int k = idx / N, n = idx % N;
    float v = W[idx];
    unsigned short h = f2bf(v);
    unsigned short l = f2bf(v - bf2f(h));
    int klo = k & 31;
    int pos = (k & ~31) + ((klo & 15) >> 2) * 8 + ((klo >> 4) & 1) * 4 + (klo & 3);
    Wh[(size_t)n * K + pos] = h;
    Wl[(size_t)n * K + pos] = l;
}

// ---------------- split-bf16 MFMA GEMM: C[M,N] = A[M,K] * W[K,N] --------
// EPI: +bias+relu. OUTBF: bf16 output. ABF: A is exact bf16 (no lo part, 2 MFMA passes).
template <bool EPI, bool OUTBF, bool ABF>
__global__ __launch_bounds__(256) void mgemm(const void* __restrict__ Av,
                                             const unsigned short* __restrict__ Wh,
                                             const unsigned short* __restrict__ Wl,
                                             const float* __restrict__ bias,
                                             void* __restrict__ Cv,
                                             int M, int N, int K) {
    __shared__ unsigned short Ah[64 * 64];
    __shared__ unsigned short Al[(ABF ? 1 : 64) * 64];
    __shared__ unsigned short Bh[64 * 64], Bl[64 * 64];
    const int tid = threadIdx.x;
    const int bm = blockIdx.y * 64;
    const int bn = blockIdx.x * 64;
    const int wid = tid >> 6, lane = tid & 63;
    const int wr = (wid >> 1) * 32, wc = (wid & 1) * 32;
    const int l15 = lane & 15, lg = lane >> 4;

    const float* Af = (const float*)Av;
    const unsigned short* Ab = (const unsigned short*)Av;

    f32x4 acc[2][2] = {};

    // f32-A staging map
    const int srow = tid >> 4;
    const int sk0 = (tid & 15) * 4;
    const int sb = (sk0 >> 5) * 64 + (((sk0 & 15) >> 2) * 8 + ((sk0 >> 4) & 1) * 4) * 2;
    // bf16-A staging map
    const int srow2 = tid >> 3;
    const int sk0b = (tid & 7) * 8;
    const int sb0 = (sk0b >> 5) * 64 + (((sk0b & 15) >> 2) * 8 + ((sk0b >> 4) & 1) * 4) * 2;
    const int sk1b = sk0b + 4;
    const int sb1 = (sk1b >> 5) * 64 + (((sk1b & 15) >> 2) * 8 + ((sk1b >> 4) & 1) * 4) * 2;
    // B staging map
    const int bcol = tid >> 2;
    const int bck = (tid & 3) * 32;

    for (int kt = 0; kt < K; kt += 64) {
        if constexpr (!ABF) {
#pragma unroll
            for (int p = 0; p < 4; ++p) {
                const int row = p * 16 + srow;
                const int gr = bm + row;
                float4 v = make_float4(0.f, 0.f, 0.f, 0.f);
                if (gr < M) v = *(const float4*)&Af[(size_t)gr * K + kt + sk0];
                const unsigned short h0 = f2bf(v.x), h1 = f2bf(v.y), h2 = f2bf(v.z),
                                     h3 = f2bf(v.w);
                const unsigned short l0 = f2bf(v.x - bf2f(h0)), l1 = f2bf(v.y - bf2f(h1));
                const unsigned short l2 = f2bf(v.z - bf2f(h2)), l3 = f2bf(v.w - bf2f(h3));
                const int byte = sb ^ ((row & 7) << 4);
                *(ushort4*)((char*)Ah + row * 128 + byte) = make_ushort4(h0, h1, h2, h3);
                *(ushort4*)((char*)Al + row * 128 + byte) = make_ushort4(l0, l1, l2, l3);
            }
        } else {
#pragma unroll
            for (int p = 0; p < 2; ++p) {
                const int row = p * 32 + srow2;
                const int gr = bm + row;
                u16x8 v = {0, 0, 0, 0, 0, 0, 0, 0};
                if (gr < M) v = *(const u16x8*)&Ab[(size_t)gr * K + kt + sk0b];
                const int sw = (row & 7) << 4;
                *(ushort4*)((char*)Ah + row * 128 + (sb0 ^ sw)) =
                    make_ushort4(v[0], v[1], v[2], v[3]);
                *(ushort4*)((char*)Ah + row * 128 + (sb1 ^ sw)) =
                    make_ushort4(v[4], v[5], v[6], v[7]);
            }
        }
        {
            const unsigned short* gh = &Wh[(size_t)(bn + bcol) * K + kt + (bck >> 1)];
            const unsigned short* gl = &Wl[(size_t)(bn + bcol) * K + kt + (bck >> 1)];
            const int byt0 = bck ^ ((bcol & 7) << 4);
            const int byt1 = (bck + 16) ^ ((bcol & 7) << 4);
            *(u16x8*)((char*)Bh + bcol * 128 + byt0) = *(const u16x8*)gh;
            *(u16x8*)((char*)Bh + bcol * 128 + byt1) = *(const u16x8*)(gh + 8);
            *(u16x8*)((char*)Bl + bcol * 128 + byt0) = *(const u16x8*)gl;
            *(u16x8*)((char*)Bl + bcol * 128 + byt1) = *(const u16x8*)(gl + 8);
        }
        __syncthreads();
#pragma unroll
        for (int kk = 0; kk < 2; ++kk) {
            s16x8 ah[2], al[2], bh[2], bl[2];
#pragma unroll
            for (int rf = 0; rf < 2; ++rf) {
                const int row = wr + rf * 16 + l15;
                const int byte = (kk * 64 + lg * 16) ^ ((row & 7) << 4);
                ah[rf] = *(const s16x8*)((const char*)Ah + row * 128 + byte);
                if constexpr (!ABF)
                    al[rf] = *(const s16x8*)((const char*)Al + row * 128 + byte);
            }
#pragma unroll
            for (int cf = 0; cf < 2; ++cf) {
                const int col = wc + cf * 16 + l15;
                const int byte = (kk * 64 + lg * 16) ^ ((col & 7) << 4);
                bh[cf] = *(const s16x8*)((const char*)Bh + col * 128 + byte);
                bl[cf] = *(const s16x8*)((const char*)Bl + col * 128 + byte);
            }
#pragma unroll
            for (int rf = 0; rf < 2; ++rf)
#pragma unroll
                for (int cf = 0; cf < 2; ++cf) {
                    acc[rf][cf] = __builtin_amdgcn_mfma_f32_16x16x32_bf16(ah[rf], bh[cf],
                                                                          acc[rf][cf], 0, 0, 0);
                    acc[rf][cf] = __builtin_amdgcn_mfma_f32_16x16x32_bf16(ah[rf], bl[cf],
                                                                          acc[rf][cf], 0, 0, 0);
                    if constexpr (!ABF)
                        acc[rf][cf] = __builtin_amdgcn_mfma_f32_16x16x32_bf16(
                            al[rf], bh[cf], acc[rf][cf], 0, 0, 0);
                }
        }
        __syncthreads();
    }
    // ---- epilogue: C/D layout col=lane&15, row=(lane>>4)*4+reg (m89-verified)
#pragma unroll
    for (int rf = 0; rf < 2; ++rf)
#pragma unroll
        for (int cf = 0; cf < 2; ++cf) {
            const int col = bn + wc + cf * 16 + l15;
            const float bv = EPI ? bias[col] : 0.f;
#pragma unroll
            for (int r = 0; r < 4; ++r) {
                const int gr = bm + wr + rf * 16 + lg * 4 + r;
                if (gr < M) {
                    float v = acc[rf][cf][r];
                    if (EPI) v = fmaxf(v + bv, 0.f);
                    if constexpr (OUTBF)
                        ((unsigned short*)Cv)[(size_t)gr * N + col] = f2bf(v);
                    else
                        ((float*)Cv)[(size_t)gr * N + col] = v;
                }
            }
        }
}

// ---------------- CSR aggregate over bf16 rows (paired half-waves) ----------------
// lanes 0-31 process edge e, lanes 32-63 edge e+1; uint2 (4 bf16) per lane;
// __shfl_xor(32) combines halves; low half writes float4.
template <bool BIAS_RELU>
__global__ __launch_bounds__(256) void k_agg(const int* __restrict__ row_ptr,
                                             const unsigned short* __restrict__ e_src,
                                             const unsigned short* __restrict__ hb,
                                             const float* __restrict__ dinv,
                                             const float* __restrict__ bias,
                                             float* __restrict__ out, int n) {
    const int node = (blockIdx.x * 256 + threadIdx.x) >> 6;
    const int lane = threadIdx.x & 63;
    const int half = lane >> 5, l32 = lane & 31;
    if (node >= n) return;
    const int beg = row_ptr[node], end = row_ptr[node + 1];
    const float dn = dinv[node];

    float a0 = 0.f, a1 = 0.f, a2 = 0.f, a3 = 0.f;
    int e = beg;
    for (; e + 7 < end; e += 8) {
        const int s0 = e_src[e + half], s1 = e_src[e + 2 + half];
        const int s2 = e_src[e + 4 + half], s3 = e_src[e + 6 + half];
        const float n0 = dinv[s0] * dn, n1 = dinv[s1] * dn;
        const float n2 = dinv[s2] * dn, n3 = dinv[s3] * dn;
        const uint2 v0 = *(const uint2*)&hb[(size_t)s0 * 128 + l32 * 4];
        const uint2 v1 = *(const uint2*)&hb[(size_t)s1 * 128 + l32 * 4];
        const uint2 v2 = *(const uint2*)&hb[(size_t)s2 * 128 + l32 * 4];
        const uint2 v3 = *(const uint2*)&hb[(size_t)s3 * 128 + l32 * 4];
        a0 += blo(v0.x) * n0 + blo(v1.x) * n1 + blo(v2.x) * n2 + blo(v3.x) * n3;
        a1 += bhi(v0.x) * n0 + bhi(v1.x) * n1 + bhi(v2.x) * n2 + bhi(v3.x) * n3;
        a2 += blo(v0.y) * n0 + blo(v1.y) * n1 + blo(v2.y) * n2 + blo(v3.y) * n3;
        a3 += bhi(v0.y) * n0 + bhi(v1.y) * n1 + bhi(v2.y) * n2 + bhi(v3.y) * n3;
    }
    for (; e + 1 < end; e += 2) {
        const int s = e_src[e + half];
        const float nr = dinv[s] * dn;
        const uint2 v = *(const uint2*)&hb[(size_t)s * 128 + l32 * 4];
        a0 += blo(v.x) * nr;
        a1 += bhi(v.x) * nr;
        a2 += blo(v.y) * nr;
        a3 += bhi(v.y) * nr;
    }
    if (e < end && half == 0) {
        const int s = e_src[e];
        const float nr = dinv[s] * dn;
        const uint2 v = *(const uint2*)&hb[(size_t)s * 128 + l32 * 4];
        a0 += blo(v.x) * nr;
        a1 += bhi(v.x) * nr;
        a2 += blo(v.y) * nr;
        a3 += bhi(v.y) * nr;
    }
    // combine the two half-wave partials (same cols, disjoint edges)
    a0 += __shfl_xor(a0, 32, 64);
    a1 += __shfl_xor(a1, 32, 64);
    a2 += __shfl_xor(a2, 32, 64);
    a3 += __shfl_xor(a3, 32, 64);

    if (half == 0) {
        const uint2 vs = *(const uint2*)&hb[(size_t)node * 128 + l32 * 4];
        const float d2 = dn * dn;
        a0 += blo(vs.x) * d2;
        a1 += bhi(vs.x) * d2;
        a2 += blo(vs.y) * d2;
        a3 += bhi(vs.y) * d2;
        if constexpr (BIAS_RELU) {
            const float4 bv = *(const float4*)&bias[l32 * 4];
            a0 = fmaxf(a0 + bv.x, 0.f);
            a1 = fmaxf(a1 + bv.y, 0.f);
            a2 = fmaxf(a2 + bv.z, 0.f);
            a3 = fmaxf(a3 + bv.w, 0.f);
        }
        *(float4*)&out[(size_t)node * 128 + l32 * 4] = make_float4(a0, a1, a2, a3);
    }
}

extern "C" void kernel_launch(void* const* d_in, const int* in_sizes, int n_in,
                              void* d_out, int out_size, void* d_ws, size_t ws_size,
                              hipStream_t stream) {
    const float* x[2] = {(const float*)d_in[0], (const float*)d_in[2]};
    const int* eidx[2] = {(const int*)d_in[1], (const int*)d_in[3]};
    const int E[2] = {in_sizes[1] / 2, in_sizes[3] / 2};
    const float* W1 = (const float*)d_in[4];
    const float* b1 = (const float*)d_in[5];
    const float* W2 = (const float*)d_in[6];
    const float* b2 = (const float*)d_in[7];
    float* out = (float*)d_out;

    const int Emax = (E[0] > E[1]) ? E[0] : E[1];
    char* ws = (char*)d_ws;
    size_t off = 0;
    auto alloc = [&](size_t bytes) -> void* {
        void* p = ws + off;
        off = (off + bytes + 255) & ~(size_t)255;
        return p;
    };
    float* aggX = (float*)alloc((size_t)NN * 128 * 4);                    // Âx (f32, GEMM1 A)
    unsigned short* x1_bf = (unsigned short*)alloc((size_t)NN * 256 * 2); // layer-1 act (bf16)
    unsigned short* x_bf = (unsigned short*)alloc((size_t)NN * 128 * 2);  // x in bf16 (gather)
    unsigned short* h2_bf = (unsigned short*)alloc((size_t)NN * 128 * 2); // h2 in bf16 (gather)
    unsigned short* W1h = (unsigned short*)alloc(128 * 256 * 2);
    unsigned short* W1l = (unsigned short*)alloc(128 * 256 * 2);
    unsigned short* W2h = (unsigned short*)alloc(256 * 128 * 2);
    unsigned short* W2l = (unsigned short*)alloc(256 * 128 * 2);
    int* deg = (int*)alloc((size_t)NN * 4);
    float* dinv = (float*)alloc((size_t)NN * 4);
    int* rowp = (int*)alloc((size_t)(NN + 1) * 4);
    int* cursor = (int*)alloc((size_t)NN * 4);
    int* bsum = (int*)alloc(64 * 4);
    int* boff = (int*)alloc(64 * 4);
    unsigned short* e_src = (unsigned short*)alloc((size_t)Emax * 2);

    const int NB = (NN + 1023) / 1024;  // 49

    // weights: convert+transpose+permute once per call
    k_wcvt<<<(128 * 256 + 255) / 256, 256, 0, stream>>>(W1, W1h, W1l, 128, 256);
    k_wcvt<<<(256 * 128 + 255) / 256, 256, 0, stream>>>(W2, W2h, W2l, 256, 128);

    for (int g = 0; g < 2; ++g) {
        const int Eg = E[g];
        const int* srcp = eidx[g];
        const int* dstp = eidx[g] + Eg;

        // ---- CSR build + x convert
        hipMemsetAsync(deg, 0, NN * sizeof(int), stream);
        k_cvt_bf<<<(NN * 128 / 4 + 255) / 256, 256, 0, stream>>>(x[g], x_bf, NN * 128 / 4);
        k_deg<<<(Eg + 255) / 256, 256, 0, stream>>>(dstp, Eg, deg);
        k_bsum_dinv<<<NB, 1024, 0, stream>>>(deg, dinv, bsum, NN);
        k_pscan<<<1, 64, 0, stream>>>(bsum, boff, NB, &rowp[NN], Eg);
        k_scan2<<<NB, 1024, 0, stream>>>(deg, boff, rowp, cursor, NN);
        k_bin<<<(Eg + 255) / 256, 256, 0, stream>>>(srcp, dstp, cursor, e_src, Eg);

        // ---- layer 1 (aggregate-first): aggX = Â x ; x1 = relu(aggX @ W1 + b1) [bf16]
        k_agg<false><<<(NN + 3) / 4, 256, 0, stream>>>(rowp, e_src, x_bf, dinv, nullptr,
                                                       aggX, NN);
        mgemm<true, true, false><<<dim3(256 / 64, (NN + 63) / 64), 256, 0, stream>>>(
            aggX, W1h, W1l, b1, x1_bf, NN, 256, 128);

        // ---- layer 2 (aggregate-last): h2 = x1 @ W2 (bf16 A, 2-pass); out = relu(Â h2 + b2)
        mgemm<false, true, true><<<dim3(128 / 64, (NN + 63) / 64), 256, 0, stream>>>(
            x1_bf, W2h, W2l, nullptr, h2_bf, NN, 128, 256);
        k_agg<true><<<(NN + 3) / 4, 256, 0, stream>>>(rowp, e_src, h2_bf, dinv, b2,
                                                      out + (size_t)g * NN * 128, NN);
    }
}